// Round 1
// baseline (141.450 us; speedup 1.0000x reference)
//
#include <hip/hip_runtime.h>

#define TEMP 0.05f
#define EPS 1e-8f
#define NROWS 16384
#define DDIM 1024
#define NBLOCKS (NROWS / 4)   // 4 waves/block, 1 row/wave

__global__ __launch_bounds__(256) void byol_rows_kernel(
        const float* __restrict__ a, const float* __restrict__ b,
        float* __restrict__ partials) {
    const int wave = threadIdx.x >> 6;
    const int lane = threadIdx.x & 63;
    const int row  = blockIdx.x * 4 + wave;

    const float4* a4 = (const float4*)(a + (size_t)row * DDIM);
    const float4* b4 = (const float4*)(b + (size_t)row * DDIM);

    float dot = 0.f, aa = 0.f, bb = 0.f;
#pragma unroll
    for (int j = 0; j < 4; ++j) {
        float4 av = a4[lane + 64 * j];
        float4 bv = b4[lane + 64 * j];
        dot += av.x * bv.x + av.y * bv.y + av.z * bv.z + av.w * bv.w;
        aa  += av.x * av.x + av.y * av.y + av.z * av.z + av.w * av.w;
        bb  += bv.x * bv.x + bv.y * bv.y + bv.z * bv.z + bv.w * bv.w;
    }

#pragma unroll
    for (int off = 32; off > 0; off >>= 1) {
        dot += __shfl_down(dot, off, 64);
        aa  += __shfl_down(aa,  off, 64);
        bb  += __shfl_down(bb,  off, 64);
    }

    __shared__ float s[4];
    if (lane == 0) {
        float n1 = fmaxf(sqrtf(aa), EPS);
        float n2 = fmaxf(sqrtf(bb), EPS);
        float c  = dot / (n1 * n2);
        s[wave]  = 2.0f - 2.0f * c;
    }
    __syncthreads();
    if (threadIdx.x == 0) {
        partials[blockIdx.x] = s[0] + s[1] + s[2] + s[3];
    }
}

__global__ __launch_bounds__(256) void byol_final_kernel(
        const float* __restrict__ partials, float* __restrict__ out) {
    float sum = 0.f;
#pragma unroll
    for (int j = 0; j < NBLOCKS / 256; ++j)
        sum += partials[threadIdx.x + 256 * j];

#pragma unroll
    for (int off = 32; off > 0; off >>= 1)
        sum += __shfl_down(sum, off, 64);

    __shared__ float s[4];
    const int wave = threadIdx.x >> 6;
    const int lane = threadIdx.x & 63;
    if (lane == 0) s[wave] = sum;
    __syncthreads();
    if (threadIdx.x == 0) {
        out[0] = (s[0] + s[1] + s[2] + s[3]) * (1.0f / ((float)NROWS * TEMP));
    }
}

extern "C" void kernel_launch(void* const* d_in, const int* in_sizes, int n_in,
                              void* d_out, int out_size, void* d_ws, size_t ws_size,
                              hipStream_t stream) {
    const float* a = (const float*)d_in[0];
    const float* b = (const float*)d_in[1];
    float* out = (float*)d_out;
    float* partials = (float*)d_ws;   // NBLOCKS floats = 16 KB

    byol_rows_kernel<<<NBLOCKS, 256, 0, stream>>>(a, b, partials);
    byol_final_kernel<<<1, 256, 0, stream>>>(partials, out);
}